// Round 18
// baseline (280.404 us; speedup 1.0000x reference)
//
#include <hip/hip_runtime.h>
#include <hip/hip_bf16.h>

#define SEQ 2048

typedef float f32x4 __attribute__((ext_vector_type(4)));
typedef float f32x16 __attribute__((ext_vector_type(16)));
typedef short short8 __attribute__((ext_vector_type(8)));
typedef int int4v __attribute__((ext_vector_type(4)));

static __device__ __forceinline__ unsigned short f2bf(float f) {
  __hip_bfloat16 h = __float2bfloat16(f);
  unsigned short u;
  __builtin_memcpy(&u, &h, 2);
  return u;
}
static __device__ __forceinline__ float bf2f(unsigned short u) {
  __hip_bfloat16 h;
  __builtin_memcpy(&h, &u, 2);
  return __bfloat162float(h);
}
static __device__ __forceinline__ void gload16(const void* g, void* l) {
  __builtin_amdgcn_global_load_lds(
      (const __attribute__((address_space(1))) void*)g,
      (__attribute__((address_space(3))) void*)l, 16, 0, 0);
}
// gelu(tanh approx) == x * sigmoid(1.59577x + 0.0713548x^3), sigmoid in exp2 domain
static __device__ __forceinline__ float gelu_t(float x) {
  float t = x * x;
  float z = x * fmaf(0.1029442695044937f, t, 2.3021181827964594f);  // pre-multiplied log2(e)
  return x * __builtin_amdgcn_rcpf(1.f + exp2f(-z));
}
static __device__ __forceinline__ unsigned int cvtpk(float lo, float hi) {
  unsigned int r;
  asm("v_cvt_pk_bf16_f32 %0, %1, %2" : "=v"(r) : "v"(lo), "v"(hi));
  return r;
}
// partial RoPE pair rotation for channel pair (2i, 2i+1) at sequence position pos
static __device__ __forceinline__ void rope_pair(short8& v, int m, int i, float pos) {
  const float fr = exp2f(-(float)(2 * i) * (13.287712379549449f / 64.f));  // 10000^(-2i/64)
  const float ang = pos * fr;
  const float sn = sinf(ang), cs = cosf(ang);
  const float x0 = bf2f((unsigned short)v[2 * m]);
  const float x1 = bf2f((unsigned short)v[2 * m + 1]);
  v[2 * m] = (short)f2bf(x0 * cs - x1 * sn);
  v[2 * m + 1] = (short)f2bf(x1 * cs + x0 * sn);
}

// ---------------- prep kernels ----------------

#define SOFTMAX_M0 16.0f
// merged: 4x weight transpose (blocks 0..12287) + silu(c) (12288..12295) +
// rel-position bias table (12296..12551). brp pre-scaled by log2(e), pre-shifted -M0.
__global__ void prep_transpose(const float* __restrict__ w_qkv, const float* __restrict__ w_out,
                               const float* __restrict__ w_mlp1, const float* __restrict__ w_mlp2,
                               unsigned short* __restrict__ dq, unsigned short* __restrict__ dwo,
                               unsigned short* __restrict__ dm1, unsigned short* __restrict__ dm2,
                               const float* __restrict__ c, float* __restrict__ siluc,
                               const float* __restrict__ rel_table, float* __restrict__ brp) {
  const int bid = blockIdx.x;
  const int t = threadIdx.x;
  if (bid >= 12288) {
    const int pb = bid - 12288;
    if (pb < 8) {
      int i = pb * 256 + t;  // 2048
      float v = c[i];
      siluc[i] = v / (1.f + expf(-v));
    } else {
      int idx = (pb - 8) * 256 + t;  // 16*4096
      int h = idx >> 12, pos = idx & 4095;
      int rp = pos - 2047;
      int bucket = rp > 0 ? 16 : 0;
      int a = rp < 0 ? -rp : rp;
      int bi;
      if (a < 8) {
        bi = a;
      } else {
        bi = 8 + (int)(logf((float)a / 8.f) / 2.772588722239781f * 8.f);
        if (bi > 15) bi = 15;
      }
      brp[idx] = rel_table[(bucket + bi) * 16 + h] * 1.4426950408889634f - SOFTMAX_M0;
    }
    return;
  }
  __shared__ float tile[32][33];
  const float* src;
  unsigned short* dst;
  int K, N, NT, r;
  if (bid < 3072) {
    src = w_qkv; dst = dq; K = 1024; N = 3072; NT = 96; r = bid;
  } else if (bid < 4096) {
    src = w_out; dst = dwo; K = 1024; N = 1024; NT = 32; r = bid - 3072;
  } else if (bid < 8192) {
    src = w_mlp1; dst = dm1; K = 1024; N = 4096; NT = 128; r = bid - 4096;
  } else {
    src = w_mlp2; dst = dm2; K = 4096; N = 1024; NT = 32; r = bid - 8192;
  }
  const int nt = r % NT, kt = r / NT;
  const int col = t & 31, r0 = t >> 5;
#pragma unroll
  for (int i = 0; i < 4; ++i) {
    int rr = r0 + i * 8;
    tile[rr][col] = src[(size_t)(kt * 32 + rr) * N + nt * 32 + col];
  }
  __syncthreads();
#pragma unroll
  for (int i = 0; i < 4; ++i) {
    int rr = r0 + i * 8;
    dst[(size_t)(nt * 32 + rr) * K + kt * 32 + col] = f2bf(tile[col][rr]);
  }
}

// single-kernel mod GEMM: mod[b][j] = silu(c)[b,:] @ w_ada[:,j] + b_ada[j]
// 48 blocks x 256 threads; block covers 256 consecutive j of one b. silu(c) row
// cached in LDS; w_ada reads coalesced (256 consecutive floats per k step).
__global__ void mod_k(const float* __restrict__ siluc, const float* __restrict__ w_ada,
                      const float* __restrict__ b_ada, float* __restrict__ mod) {
  __shared__ float cs[1024];
  const int blk = blockIdx.x;  // 0..47
  const int b = blk / 24;
  const int j0 = (blk % 24) * 256;
  const int t = threadIdx.x;
  const float4 cv = ((const float4*)(siluc + b * 1024))[t];
  ((float4*)cs)[t] = cv;
  __syncthreads();
  const int j = j0 + t;
  const float* wp = w_ada + j;
  float acc = b_ada[j];
#pragma unroll 8
  for (int k = 0; k < 1024; ++k) acc = fmaf(cs[k], wp[(size_t)k * 6144], acc);
  mod[b * 6144 + j] = acc;
}

// LayerNorm + adaLN modulation -> bf16
__global__ void ln_mod(const float* __restrict__ x, const float* __restrict__ mod,
                       unsigned short* __restrict__ out, int sh_off, int sc_off) {
  int row = blockIdx.x;
  int b = row >> 11;
  int t = threadIdx.x;
  const float4 v = ((const float4*)(x + (size_t)row * 1024))[t];
  float s1 = v.x + v.y + v.z + v.w;
  float s2 = v.x * v.x + v.y * v.y + v.z * v.z + v.w * v.w;
#pragma unroll
  for (int off = 32; off; off >>= 1) {
    s1 += __shfl_xor(s1, off);
    s2 += __shfl_xor(s2, off);
  }
  __shared__ float red[8];
  int w = t >> 6, lane = t & 63;
  if (lane == 0) { red[w] = s1; red[4 + w] = s2; }
  __syncthreads();
  s1 = red[0] + red[1] + red[2] + red[3];
  s2 = red[4] + red[5] + red[6] + red[7];
  float mean = s1 * (1.f / 1024.f);
  float var = s2 * (1.f / 1024.f) - mean * mean;
  float rstd = rsqrtf(var + 1e-6f);
  const float* mb = mod + (size_t)b * 6144;
  int col = t * 4;
  ushort4 o4;
  o4.x = f2bf((v.x - mean) * rstd * (1.f + mb[sc_off + col + 0]) + mb[sh_off + col + 0]);
  o4.y = f2bf((v.y - mean) * rstd * (1.f + mb[sc_off + col + 1]) + mb[sh_off + col + 1]);
  o4.z = f2bf((v.z - mean) * rstd * (1.f + mb[sc_off + col + 2]) + mb[sh_off + col + 2]);
  o4.w = f2bf((v.w - mean) * rstd * (1.f + mb[sc_off + col + 3]) + mb[sh_off + col + 3]);
  *((ushort4*)(out + (size_t)row * 1024 + col)) = o4;
}

// In-place partial RoPE on kpk head 0 (reference ropes channels 0..63 only).
__global__ void krope_fix(unsigned short* __restrict__ kpk) {
  const int gid = blockIdx.x * 256 + threadIdx.x;  // 2*64*32*32 = 131072
  const int i = gid & 31;                          // pair index (d = 2i)
  const int l31 = (gid >> 5) & 31;
  const int kt = (gid >> 10) & 63;
  const int b = gid >> 16;
  const int d = 2 * i;
  const int bh = b * 16;  // h = 0
  const size_t addr = (((size_t)(bh * 64 + kt) * 4 + (d >> 4)) * 512) +
                      (((d >> 3) & 1) * 32 + l31) * 8 + (d & 7);
  unsigned int pv = *(unsigned int*)(kpk + addr);
  const float x0 = bf2f((unsigned short)(pv & 0xFFFF));
  const float x1 = bf2f((unsigned short)(pv >> 16));
  const float fr = exp2f(-(float)d * (13.287712379549449f / 64.f));
  const float ang = (float)(kt * 32 + l31) * fr;
  const float sn = sinf(ang), cs = cosf(ang);
  *(unsigned int*)(kpk + addr) =
      (unsigned int)f2bf(x0 * cs - x1 * sn) | ((unsigned int)f2bf(x1 * cs + x0 * sn) << 16);
}

// ---------------- GEMM: C = A[M,K] * Bt[N,K]^T, bf16 in, fused epilogues ----------------
// MODE 0: bf16 = acc + bias; MODE 1: bf16 = gelu(acc+bias); MODE 2: f32 = res + g*(acc+bias)
// MODE 3: qkv fused packing — Q -> qkvbuf row-major; K -> kpk fragment layout; V -> vpk
//         transposed fragment layout (block-uniform region branch).
// KS=64 (measured conflict-free swizzle). PIPE=1: double-buffered LDS, STAGE(t+1) before
// compute(t). MEASURED tile ledger (N=1024 GEMMs): 64x64 PIPE=1 = 55us best (R9/R11);
// 128x64=60.6 (R10); packed-B=68.5 (R12); 128x128 PIPE=1=71.3 (R13). Do not revisit.
template <int MODE, int BM, int BN, int PIPE>
__global__ __launch_bounds__(256) void gemm_bt(
    const unsigned short* __restrict__ A, const unsigned short* __restrict__ Bt,
    const float* __restrict__ bias, void* __restrict__ outp, const float* __restrict__ res,
    const float* __restrict__ mod, int goff, int N, int K,
    unsigned short* __restrict__ kpkp, unsigned short* __restrict__ vpkp) {
  constexpr int NBUF = PIPE ? 2 : 1;
  __shared__ __align__(16) unsigned short a_lds[NBUF][BM * 64];
  __shared__ __align__(16) unsigned short b_lds[NBUF][BN * 64];
  constexpr int WM = BM / 2, WN = BN / 2;
  constexpr int MT = WM / 16, NT = WN / 16;
  const int t = threadIdx.x;
  const int lane = t & 63;
  const int l15 = lane & 15, l4 = lane >> 4;
  const int w = t >> 6;
  const int wr = w >> 1, wc = w & 1;
  // XCD-aware bijective remap (requires nwg % 8 == 0).
  const int gx = gridDim.x;
  const int nwg = gx * gridDim.y;
  int wg = blockIdx.y * gx + blockIdx.x;
  wg = (wg & 7) * (nwg >> 3) + (wg >> 3);
  const int by = wg / gx, bx = wg - by * gx;
  const int rowA0 = by * BM;
  const int rowB0 = bx * BN;
  const int wub = t & ~63;

  f32x4 acc[MT][NT];
#pragma unroll
  for (int m = 0; m < MT; ++m)
#pragma unroll
    for (int n = 0; n < NT; ++n) acc[m][n] = (f32x4){0.f, 0.f, 0.f, 0.f};

  auto stage = [&](int buf, int kt) {
#pragma unroll
    for (int rnd = 0; rnd < BM / 32; ++rnd) {
      const int idx = rnd * 256 + t;
      const int row = idx >> 3;
      const int cb = ((idx & 7) << 4) ^ ((row & 7) << 4);  // inverse-swizzled source
      const char* sa = (const char*)(A + (size_t)(rowA0 + row) * K + kt) + cb;
      gload16(sa, (char*)(&a_lds[buf][0]) + (size_t)(rnd * 256 + wub) * 16);
    }
#pragma unroll
    for (int rnd = 0; rnd < BN / 32; ++rnd) {
      const int idx = rnd * 256 + t;
      const int row = idx >> 3;
      const int cb = ((idx & 7) << 4) ^ ((row & 7) << 4);
      const char* sb = (const char*)(Bt + (size_t)(rowB0 + row) * K + kt) + cb;
      gload16(sb, (char*)(&b_lds[buf][0]) + (size_t)(rnd * 256 + wub) * 16);
    }
  };

  auto compute = [&](int buf) {
#pragma unroll
    for (int kb = 0; kb < 2; ++kb) {
      short8 af[MT], bfr[NT];
#pragma unroll
      for (int m = 0; m < MT; ++m) {
        int row = wr * WM + m * 16 + l15;
        int cb = (kb * 64 + l4 * 16) ^ ((row & 7) << 4);
        af[m] = *(const short8*)((const char*)(&a_lds[buf][0]) + row * 128 + cb);
      }
#pragma unroll
      for (int n = 0; n < NT; ++n) {
        int row = wc * WN + n * 16 + l15;
        int cb = (kb * 64 + l4 * 16) ^ ((row & 7) << 4);
        bfr[n] = *(const short8*)((const char*)(&b_lds[buf][0]) + row * 128 + cb);
      }
      __builtin_amdgcn_s_setprio(1);
#pragma unroll
      for (int m = 0; m < MT; ++m)
#pragma unroll
        for (int n = 0; n < NT; ++n)
          acc[m][n] = __builtin_amdgcn_mfma_f32_16x16x32_bf16(af[m], bfr[n], acc[m][n], 0, 0, 0);
      __builtin_amdgcn_s_setprio(0);
    }
  };

  if (PIPE) {
    stage(0, 0);
    __syncthreads();
    int cur = 0;
    for (int kt = 0; kt < K; kt += 64) {
      if (kt + 64 < K) stage(cur ^ 1, kt + 64);  // prefetch BEFORE compute
      compute(cur);
      __syncthreads();
      cur ^= 1;
    }
  } else {
    for (int kt = 0; kt < K; kt += 64) {
      stage(0, kt);
      __syncthreads();
      compute(0);
      __syncthreads();
    }
  }

#pragma unroll
  for (int n = 0; n < NT; ++n) {
    const int col = rowB0 + wc * WN + n * 16 + l15;
    const float bv = bias[col];
#pragma unroll
    for (int m = 0; m < MT; ++m) {
      const int row0 = rowA0 + wr * WM + m * 16 + l4 * 4;
#pragma unroll
      for (int r = 0; r < 4; ++r) {
        float v = acc[m][n][r] + bv;
        if (MODE == 0) {
          ((unsigned short*)outp)[(size_t)(row0 + r) * N + col] = f2bf(v);
        } else if (MODE == 1) {
          ((unsigned short*)outp)[(size_t)(row0 + r) * N + col] = f2bf(gelu_t(v));
        } else if (MODE == 2) {
          const size_t o = (size_t)(row0 + r) * N + col;
          float g = mod[(size_t)((row0 + r) >> 11) * 6144 + goff + col];
          ((float*)outp)[o] = res[o] + g * v;
        } else {  // MODE 3: qkv fused packing
          const int rr = row0 + r;
          if (rowB0 < 1024) {  // Q: row-major into qkvbuf
            ((unsigned short*)outp)[(size_t)rr * N + col] = f2bf(v);
          } else if (rowB0 < 2048) {  // K -> kpk fragment layout
            const int bb = rr >> 11, krow = rr & 2047;
            const int colk = col - 1024;
            const int hh = colk >> 6, d = colk & 63;
            const int bh2 = bb * 16 + hh;
            const size_t addr = (((size_t)(bh2 * 64 + (krow >> 5)) * 4 + (d >> 4)) * 512) +
                                (((d >> 3) & 1) * 32 + (krow & 31)) * 8 + (d & 7);
            kpkp[addr] = f2bf(v);
          } else {  // V -> vpk transposed fragment layout
            const int bb = rr >> 11, krow = rr & 2047;
            const int colv = col - 2048;
            const int hh = colv >> 6, d = colv & 63;
            const int bh2 = bb * 16 + hh;
            const int r5 = krow & 31;
            const int f = (d >> 5) * 2 + (r5 >> 4);
            const size_t addr = (((size_t)(bh2 * 64 + (krow >> 5)) * 4 + f) * 512) +
                                (((r5 >> 3) & 1) * 32 + (d & 31)) * 8 + (r5 & 7);
            vpkp[addr] = f2bf(v);
          }
        }
      }
    }
  }
}

// ---------------- flash attention, single-pass, fixed-reference softmax ----------------
// 512 blocks (2/CU), each covers ALL 64 k-tile-units (2048 keys) for 128 q-rows.
// Instruction-issue-bound (MFMA 31% + VALU 48%); k-split measured slower (R14).
// Q RoPE fused (head 0 only). Row-sum on matrix pipe; 1/lacc[0] is the normalizer.
__global__ __launch_bounds__(256) void attn_k(const unsigned short* __restrict__ qkv,
                                              const unsigned short* __restrict__ kpk,
                                              const unsigned short* __restrict__ vpk,
                                              const float* __restrict__ brp_all,
                                              unsigned short* __restrict__ ctxv) {
  const int t = threadIdx.x;
  const int w = t >> 6;
  const int lane = t & 63;
  const int l31 = lane & 31;
  const int hi = lane >> 5;
  // XCD-aware remap (512 blocks): each XCD owns 4 bh x 16 qt.
  const int wg = blockIdx.x;
  const int xcd = wg & 7, idx = wg >> 3;  // idx 0..63
  const int bh = xcd * 4 + (idx >> 4);
  const int qt = idx & 15;
  const int b = bh >> 4, h = bh & 15;
  const int qw = qt * 128 + w * 32;  // warp's q-base
  const float SC = 0.125f * 1.4426950408889634f;
  const float* brp = brp_all + (size_t)h * 4096;

  short8 qfr[4];
  {
    const unsigned short* qrow = qkv + (size_t)(b * SEQ + qw + l31) * 3072 + h * 64 + hi * 8;
#pragma unroll
    for (int kk = 0; kk < 4; ++kk) qfr[kk] = *(const short8*)(qrow + kk * 16);
    if (h == 0) {  // fused partial RoPE on Q (head 0 carries channels 0..63)
      const float pos = (float)(qw + l31);
#pragma unroll
      for (int kk = 0; kk < 4; ++kk) {
        const int d0 = kk * 16 + hi * 8;
#pragma unroll
        for (int m = 0; m < 4; ++m) rope_pair(qfr[kk], m, (d0 >> 1) + m, pos);
      }
    }
  }
  const float bfar_pos = brp[4095], bfar_neg = brp[0];
  const float* bql = brp + 2047 + 4 * hi - (qw + l31);

  short8 ones;  // bf16 1.0 x8 — A-operand for the row-sum MFMA
#pragma unroll
  for (int i = 0; i < 8; ++i) ones[i] = (short)0x3F80;

  const unsigned short* kp = kpk + ((size_t)(bh * 64)) * 2048 + lane * 8;
  const unsigned short* vp = vpk + ((size_t)(bh * 64)) * 2048 + lane * 8;

  short8 kfrA[4], vfrA[4], kfrB[4], vfrB[4];
#pragma unroll
  for (int s = 0; s < 4; ++s) {
    kfrA[s] = *(const short8*)(kp + s * 512);
    vfrA[s] = *(const short8*)(vp + s * 512);
  }
  kp += 2048;
  vp += 2048;

  f32x16 oacc0 = {}, oacc1 = {}, lacc = {};
  int kbase = 0;

#define ATTN_TILE(KF, VF, KFN, VFN)                                                       \
  do {                                                                                    \
    KFN[0] = *(const short8*)(kp);                                                        \
    KFN[1] = *(const short8*)(kp + 512);                                                  \
    KFN[2] = *(const short8*)(kp + 1024);                                                 \
    KFN[3] = *(const short8*)(kp + 1536);                                                 \
    VFN[0] = *(const short8*)(vp);                                                        \
    VFN[1] = *(const short8*)(vp + 512);                                                  \
    VFN[2] = *(const short8*)(vp + 1024);                                                 \
    VFN[3] = *(const short8*)(vp + 1536);                                                 \
    kp += 2048;                                                                           \
    vp += 2048;                                                                           \
    f32x16 sacc = {};                                                                     \
    sacc = __builtin_amdgcn_mfma_f32_32x32x16_bf16(KF[0], qfr[0], sacc, 0, 0, 0);         \
    sacc = __builtin_amdgcn_mfma_f32_32x32x16_bf16(KF[1], qfr[1], sacc, 0, 0, 0);         \
    sacc = __builtin_amdgcn_mfma_f32_32x32x16_bf16(KF[2], qfr[2], sacc, 0, 0, 0);         \
    sacc = __builtin_amdgcn_mfma_f32_32x32x16_bf16(KF[3], qfr[3], sacc, 0, 0, 0);         \
    float p[16];                                                                          \
    const int dd = kbase - qw;                                                            \
    if (dd >= 128 || dd <= -128) {                                                        \
      const float bf_ = (dd > 0) ? bfar_pos : bfar_neg;                                   \
      _Pragma("unroll") for (int r = 0; r < 16; ++r)                                      \
          p[r] = __builtin_amdgcn_exp2f(fmaf(sacc[r], SC, bf_));                          \
    } else {                                                                              \
      const float* bp = bql + kbase;                                                      \
      _Pragma("unroll") for (int r = 0; r < 16; ++r)                                      \
          p[r] = __builtin_amdgcn_exp2f(fmaf(sacc[r], SC, bp[(r & 3) + 8 * (r >> 2)]));   \
    }                                                                                     \
    unsigned int x0 = cvtpk(p[0], p[1]), x1 = cvtpk(p[2], p[3]);                          \
    unsigned int y0 = cvtpk(p[4], p[5]), y1 = cvtpk(p[6], p[7]);                          \
    asm("v_permlane32_swap_b32 %0, %1" : "+v"(x0), "+v"(y0));                             \
    asm("v_permlane32_swap_b32 %0, %1" : "+v"(x1), "+v"(y1));                             \
    unsigned int x2 = cvtpk(p[8], p[9]), x3 = cvtpk(p[10], p[11]);                        \
    unsigned int y2 = cvtpk(p[12], p[13]), y3 = cvtpk(p[14], p[15]);                      \
    asm("v_permlane32_swap_b32 %0, %1" : "+v"(x2), "+v"(y2));                             \
    asm("v_permlane32_swap_b32 %0, %1" : "+v"(x3), "+v"(y3));                             \
    int4v pi0 = {(int)x0, (int)x1, (int)y0, (int)y1};                                     \
    int4v pi1 = {(int)x2, (int)x3, (int)y2, (int)y3};                                     \
    short8 pf0 = __builtin_bit_cast(short8, pi0);                                         \
    short8 pf1 = __builtin_bit_cast(short8, pi1);                                         \
    lacc = __builtin_amdgcn_mfma_f32_32x32x16_bf16(ones, pf0, lacc, 0, 0, 0);             \
    lacc = __builtin_amdgcn_mfma_f32_32x32x16_bf16(ones, pf1, lacc, 0, 0, 0);             \
    oacc0 = __builtin_amdgcn_mfma_f32_32x32x16_bf16(VF[0], pf0, oacc0, 0, 0, 0);          \
    oacc0 = __builtin_amdgcn_mfma_f32_32x32x16_bf16(VF[1], pf1, oacc0, 0, 0, 0);          \
    oacc1 = __builtin_amdgcn_mfma_f32_32x32x16_bf16(VF[2], pf0, oacc1, 0, 0, 0);          \
    oacc1 = __builtin_amdgcn_mfma_f32_32x32x16_bf16(VF[3], pf1, oacc1, 0, 0, 0);          \
    kbase += 32;                                                                          \
  } while (0)

#pragma unroll 1
  for (int it = 0; it < 32; ++it) {  // 64 units = all 2048 keys
    ATTN_TILE(kfrA, vfrA, kfrB, vfrB);
    ATTN_TILE(kfrB, vfrB, kfrA, vfrA);
  }
#undef ATTN_TILE

  const float inv = 1.f / lacc[0];
  unsigned short* orow = ctxv + (size_t)(b * SEQ + qw + l31) * 1024 + h * 64;
#pragma unroll
  for (int r = 0; r < 16; r += 2) {
    const int d = (r & 3) + 8 * (r >> 2) + 4 * hi;
    *(unsigned int*)(orow + d) = cvtpk(oacc0[r] * inv, oacc0[r + 1] * inv);
    *(unsigned int*)(orow + 32 + d) = cvtpk(oacc1[r] * inv, oacc1[r + 1] * inv);
  }
}

// ---------------- launch ----------------
extern "C" void kernel_launch(void* const* d_in, const int* in_sizes, int n_in, void* d_out,
                              int out_size, void* d_ws, size_t ws_size, hipStream_t stream) {
  (void)in_sizes; (void)n_in; (void)out_size; (void)ws_size;
  const float* x = (const float*)d_in[0];
  const float* c = (const float*)d_in[1];
  const float* w_ada = (const float*)d_in[2];
  const float* b_ada = (const float*)d_in[3];
  const float* w_qkv = (const float*)d_in[4];
  const float* b_qkv = (const float*)d_in[5];
  const float* w_out = (const float*)d_in[6];
  const float* b_out = (const float*)d_in[7];
  const float* rel_t = (const float*)d_in[8];
  const float* w_mlp1 = (const float*)d_in[9];
  const float* b_mlp1 = (const float*)d_in[10];
  const float* w_mlp2 = (const float*)d_in[11];
  const float* b_mlp2 = (const float*)d_in[12];
  float* out = (float*)d_out;
  char* ws = (char*)d_ws;

  constexpr size_t OFF_WQKVT = 0;
  constexpr size_t OFF_WOUTT = OFF_WQKVT + (size_t)3072 * 1024 * 2;
  constexpr size_t OFF_WM1T = OFF_WOUTT + (size_t)1024 * 1024 * 2;
  constexpr size_t OFF_WM2T = OFF_WM1T + (size_t)4096 * 1024 * 2;
  constexpr size_t OFF_H = OFF_WM2T + (size_t)1024 * 4096 * 2;
  constexpr size_t OFF_QKV = OFF_H + (size_t)4096 * 1024 * 2;
  constexpr size_t OFF_VT = OFF_QKV + (size_t)4096 * 3072 * 2;   // vpk (8.4 MB)
  constexpr size_t OFF_CTXV = OFF_VT + (size_t)32 * 64 * 2048 * 2;
  constexpr size_t OFF_MID = OFF_CTXV + (size_t)4096 * 1024 * 2;  // kpk overlays MID[0:8.4M]
  constexpr size_t OFF_SILU = OFF_MID + (size_t)4096 * 4096 * 2;
  constexpr size_t OFF_MOD = OFF_SILU + 2048 * 4;
  constexpr size_t OFF_BRP = OFF_MOD + 12288 * 4;

  unsigned short* wqkvT = (unsigned short*)(ws + OFF_WQKVT);
  unsigned short* woutT = (unsigned short*)(ws + OFF_WOUTT);
  unsigned short* wm1T = (unsigned short*)(ws + OFF_WM1T);
  unsigned short* wm2T = (unsigned short*)(ws + OFF_WM2T);
  unsigned short* hbuf = (unsigned short*)(ws + OFF_H);
  unsigned short* qkvbuf = (unsigned short*)(ws + OFF_QKV);
  unsigned short* vpkbuf = (unsigned short*)(ws + OFF_VT);
  unsigned short* ctxvbuf = (unsigned short*)(ws + OFF_CTXV);
  unsigned short* midbuf = (unsigned short*)(ws + OFF_MID);
  unsigned short* kpkbuf = (unsigned short*)(ws + OFF_MID);  // dead region during attn
  float* siluc = (float*)(ws + OFF_SILU);
  float* modb = (float*)(ws + OFF_MOD);
  float* brp = (float*)(ws + OFF_BRP);

  prep_transpose<<<12552, 256, 0, stream>>>(w_qkv, w_out, w_mlp1, w_mlp2, wqkvT, woutT, wm1T,
                                            wm2T, c, siluc, rel_t, brp);
  mod_k<<<48, 256, 0, stream>>>(siluc, w_ada, b_ada, modb);

  ln_mod<<<4096, 256, 0, stream>>>(x, modb, hbuf, 0, 1024);
  // qkv GEMM with fused K/V fragment packing
  gemm_bt<3, 128, 128, 0><<<dim3(24, 32), 256, 0, stream>>>(hbuf, wqkvT, b_qkv, qkvbuf, nullptr,
                                                            nullptr, 0, 3072, 1024, kpkbuf,
                                                            vpkbuf);
  krope_fix<<<512, 256, 0, stream>>>(kpkbuf);
  attn_k<<<512, 256, 0, stream>>>(qkvbuf, kpkbuf, vpkbuf, brp, ctxvbuf);
  // x1 = x + g_msa * (ctxv @ w_out + b_out)  (64x64 PIPE=1: measured best)
  gemm_bt<2, 64, 64, 1><<<dim3(16, 64), 256, 0, stream>>>(ctxvbuf, woutT, b_out, out, x, modb,
                                                          2048, 1024, 1024, nullptr, nullptr);
  ln_mod<<<4096, 256, 0, stream>>>(out, modb, hbuf, 3072, 4096);
  gemm_bt<1, 128, 128, 0><<<dim3(32, 32), 256, 0, stream>>>(hbuf, wm1T, b_mlp1, midbuf, nullptr,
                                                            nullptr, 0, 4096, 1024, nullptr,
                                                            nullptr);
  // out = x1 + g_mlp * (mid @ w_mlp2 + b_mlp2)  (64x64 PIPE=1)
  gemm_bt<2, 64, 64, 1><<<dim3(16, 64), 256, 0, stream>>>(midbuf, wm2T, b_mlp2, out, out, modb,
                                                          5120, 1024, 4096, nullptr, nullptr);
}

// Round 19
// 238.801 us; speedup vs baseline: 1.1742x; 1.1742x over previous
//
#include <hip/hip_runtime.h>
#include <hip/hip_bf16.h>

#define SEQ 2048

typedef float f32x4 __attribute__((ext_vector_type(4)));
typedef float f32x16 __attribute__((ext_vector_type(16)));
typedef short short8 __attribute__((ext_vector_type(8)));
typedef int int4v __attribute__((ext_vector_type(4)));

static __device__ __forceinline__ unsigned short f2bf(float f) {
  __hip_bfloat16 h = __float2bfloat16(f);
  unsigned short u;
  __builtin_memcpy(&u, &h, 2);
  return u;
}
static __device__ __forceinline__ float bf2f(unsigned short u) {
  __hip_bfloat16 h;
  __builtin_memcpy(&h, &u, 2);
  return __bfloat162float(h);
}
static __device__ __forceinline__ void gload16(const void* g, void* l) {
  __builtin_amdgcn_global_load_lds(
      (const __attribute__((address_space(1))) void*)g,
      (__attribute__((address_space(3))) void*)l, 16, 0, 0);
}
// gelu(tanh approx) == x * sigmoid(1.59577x + 0.0713548x^3), sigmoid in exp2 domain
static __device__ __forceinline__ float gelu_t(float x) {
  float t = x * x;
  float z = x * fmaf(0.1029442695044937f, t, 2.3021181827964594f);  // pre-multiplied log2(e)
  return x * __builtin_amdgcn_rcpf(1.f + exp2f(-z));
}
static __device__ __forceinline__ unsigned int cvtpk(float lo, float hi) {
  unsigned int r;
  asm("v_cvt_pk_bf16_f32 %0, %1, %2" : "=v"(r) : "v"(lo), "v"(hi));
  return r;
}
// partial RoPE pair rotation for channel pair (2i, 2i+1) at sequence position pos
static __device__ __forceinline__ void rope_pair(short8& v, int m, int i, float pos) {
  const float fr = exp2f(-(float)(2 * i) * (13.287712379549449f / 64.f));  // 10000^(-2i/64)
  const float ang = pos * fr;
  const float sn = sinf(ang), cs = cosf(ang);
  const float x0 = bf2f((unsigned short)v[2 * m]);
  const float x1 = bf2f((unsigned short)v[2 * m + 1]);
  v[2 * m] = (short)f2bf(x0 * cs - x1 * sn);
  v[2 * m + 1] = (short)f2bf(x1 * cs + x0 * sn);
}

// ---------------- prep kernels ----------------

#define SOFTMAX_M0 16.0f
// merged: 4x weight transpose (blocks 0..12287) + silu(c) (12288..12295) +
// rel-position bias table (12296..12551). brp pre-scaled by log2(e), pre-shifted -M0.
__global__ void prep_transpose(const float* __restrict__ w_qkv, const float* __restrict__ w_out,
                               const float* __restrict__ w_mlp1, const float* __restrict__ w_mlp2,
                               unsigned short* __restrict__ dq, unsigned short* __restrict__ dwo,
                               unsigned short* __restrict__ dm1, unsigned short* __restrict__ dm2,
                               const float* __restrict__ c, float* __restrict__ siluc,
                               const float* __restrict__ rel_table, float* __restrict__ brp) {
  const int bid = blockIdx.x;
  const int t = threadIdx.x;
  if (bid >= 12288) {
    const int pb = bid - 12288;
    if (pb < 8) {
      int i = pb * 256 + t;  // 2048
      float v = c[i];
      siluc[i] = v / (1.f + expf(-v));
    } else {
      int idx = (pb - 8) * 256 + t;  // 16*4096
      int h = idx >> 12, pos = idx & 4095;
      int rp = pos - 2047;
      int bucket = rp > 0 ? 16 : 0;
      int a = rp < 0 ? -rp : rp;
      int bi;
      if (a < 8) {
        bi = a;
      } else {
        bi = 8 + (int)(logf((float)a / 8.f) / 2.772588722239781f * 8.f);
        if (bi > 15) bi = 15;
      }
      brp[idx] = rel_table[(bucket + bi) * 16 + h] * 1.4426950408889634f - SOFTMAX_M0;
    }
    return;
  }
  __shared__ float tile[32][33];
  const float* src;
  unsigned short* dst;
  int K, N, NT, r;
  if (bid < 3072) {
    src = w_qkv; dst = dq; K = 1024; N = 3072; NT = 96; r = bid;
  } else if (bid < 4096) {
    src = w_out; dst = dwo; K = 1024; N = 1024; NT = 32; r = bid - 3072;
  } else if (bid < 8192) {
    src = w_mlp1; dst = dm1; K = 1024; N = 4096; NT = 128; r = bid - 4096;
  } else {
    src = w_mlp2; dst = dm2; K = 4096; N = 1024; NT = 32; r = bid - 8192;
  }
  const int nt = r % NT, kt = r / NT;
  const int col = t & 31, r0 = t >> 5;
#pragma unroll
  for (int i = 0; i < 4; ++i) {
    int rr = r0 + i * 8;
    tile[rr][col] = src[(size_t)(kt * 32 + rr) * N + nt * 32 + col];
  }
  __syncthreads();
#pragma unroll
  for (int i = 0; i < 4; ++i) {
    int rr = r0 + i * 8;
    dst[(size_t)(nt * 32 + rr) * K + kt * 32 + col] = f2bf(tile[col][rr]);
  }
}

// partial mod GEMM: silu(c)[2,1024] @ w_ada[1024,6144] split over 16 K-chunks
// (768 blocks = 3072 waves — keeps the 25MB w_ada stream latency-hidden; the
// single-kernel 48-block variant measured 80us (R17) vs ~4us for this chain.)
__global__ void mod_part_k(const float* __restrict__ siluc, const float* __restrict__ w_ada,
                           float* __restrict__ part) {
  int gid = blockIdx.x * 256 + threadIdx.x;  // 16*12288
  int kc = gid / 12288;
  int idx = gid - kc * 12288;
  int b = idx / 6144;
  int j = idx - b * 6144;
  const float* cp = siluc + b * 1024 + kc * 64;
  const float* wp = w_ada + (size_t)kc * 64 * 6144 + j;
  float acc = 0.f;
#pragma unroll 8
  for (int k = 0; k < 64; ++k) acc += cp[k] * wp[(size_t)k * 6144];
  part[gid] = acc;
}

__global__ void mod_reduce_k(const float* __restrict__ part, const float* __restrict__ b_ada,
                             float* __restrict__ mod) {
  int idx = blockIdx.x * 256 + threadIdx.x;  // 12288
  int j = idx % 6144;
  float a = b_ada[j];
#pragma unroll
  for (int kc = 0; kc < 16; ++kc) a += part[kc * 12288 + idx];
  mod[idx] = a;
}

// LayerNorm + adaLN modulation -> bf16
__global__ void ln_mod(const float* __restrict__ x, const float* __restrict__ mod,
                       unsigned short* __restrict__ out, int sh_off, int sc_off) {
  int row = blockIdx.x;
  int b = row >> 11;
  int t = threadIdx.x;
  const float4 v = ((const float4*)(x + (size_t)row * 1024))[t];
  float s1 = v.x + v.y + v.z + v.w;
  float s2 = v.x * v.x + v.y * v.y + v.z * v.z + v.w * v.w;
#pragma unroll
  for (int off = 32; off; off >>= 1) {
    s1 += __shfl_xor(s1, off);
    s2 += __shfl_xor(s2, off);
  }
  __shared__ float red[8];
  int w = t >> 6, lane = t & 63;
  if (lane == 0) { red[w] = s1; red[4 + w] = s2; }
  __syncthreads();
  s1 = red[0] + red[1] + red[2] + red[3];
  s2 = red[4] + red[5] + red[6] + red[7];
  float mean = s1 * (1.f / 1024.f);
  float var = s2 * (1.f / 1024.f) - mean * mean;
  float rstd = rsqrtf(var + 1e-6f);
  const float* mb = mod + (size_t)b * 6144;
  int col = t * 4;
  ushort4 o4;
  o4.x = f2bf((v.x - mean) * rstd * (1.f + mb[sc_off + col + 0]) + mb[sh_off + col + 0]);
  o4.y = f2bf((v.y - mean) * rstd * (1.f + mb[sc_off + col + 1]) + mb[sh_off + col + 1]);
  o4.z = f2bf((v.z - mean) * rstd * (1.f + mb[sc_off + col + 2]) + mb[sh_off + col + 2]);
  o4.w = f2bf((v.w - mean) * rstd * (1.f + mb[sc_off + col + 3]) + mb[sh_off + col + 3]);
  *((ushort4*)(out + (size_t)row * 1024 + col)) = o4;
}

// In-place partial RoPE on kpk head 0 (reference ropes channels 0..63 only).
__global__ void krope_fix(unsigned short* __restrict__ kpk) {
  const int gid = blockIdx.x * 256 + threadIdx.x;  // 2*64*32*32 = 131072
  const int i = gid & 31;                          // pair index (d = 2i)
  const int l31 = (gid >> 5) & 31;
  const int kt = (gid >> 10) & 63;
  const int b = gid >> 16;
  const int d = 2 * i;
  const int bh = b * 16;  // h = 0
  const size_t addr = (((size_t)(bh * 64 + kt) * 4 + (d >> 4)) * 512) +
                      (((d >> 3) & 1) * 32 + l31) * 8 + (d & 7);
  unsigned int pv = *(unsigned int*)(kpk + addr);
  const float x0 = bf2f((unsigned short)(pv & 0xFFFF));
  const float x1 = bf2f((unsigned short)(pv >> 16));
  const float fr = exp2f(-(float)d * (13.287712379549449f / 64.f));
  const float ang = (float)(kt * 32 + l31) * fr;
  const float sn = sinf(ang), cs = cosf(ang);
  *(unsigned int*)(kpk + addr) =
      (unsigned int)f2bf(x0 * cs - x1 * sn) | ((unsigned int)f2bf(x1 * cs + x0 * sn) << 16);
}

// ---------------- GEMM: C = A[M,K] * Bt[N,K]^T, bf16 in, fused epilogues ----------------
// MODE 0: bf16 = acc + bias; MODE 1: bf16 = gelu(acc+bias); MODE 2: f32 = res + g*(acc+bias)
// MODE 3: qkv fused packing — Q -> qkvbuf row-major; K -> kpk fragment layout; V -> vpk
//         transposed fragment layout (block-uniform region branch).
// KS=64 (measured conflict-free swizzle). PIPE=1: double-buffered LDS, STAGE(t+1) before
// compute(t). MEASURED tile ledger (N=1024 GEMMs): 64x64 PIPE=1 = 55us best (R9/R11);
// 128x64=60.6 (R10); packed-B=68.5 (R12); 128x128 PIPE=1=71.3 (R13). Do not revisit.
template <int MODE, int BM, int BN, int PIPE>
__global__ __launch_bounds__(256) void gemm_bt(
    const unsigned short* __restrict__ A, const unsigned short* __restrict__ Bt,
    const float* __restrict__ bias, void* __restrict__ outp, const float* __restrict__ res,
    const float* __restrict__ mod, int goff, int N, int K,
    unsigned short* __restrict__ kpkp, unsigned short* __restrict__ vpkp) {
  constexpr int NBUF = PIPE ? 2 : 1;
  __shared__ __align__(16) unsigned short a_lds[NBUF][BM * 64];
  __shared__ __align__(16) unsigned short b_lds[NBUF][BN * 64];
  constexpr int WM = BM / 2, WN = BN / 2;
  constexpr int MT = WM / 16, NT = WN / 16;
  const int t = threadIdx.x;
  const int lane = t & 63;
  const int l15 = lane & 15, l4 = lane >> 4;
  const int w = t >> 6;
  const int wr = w >> 1, wc = w & 1;
  // XCD-aware bijective remap (requires nwg % 8 == 0).
  const int gx = gridDim.x;
  const int nwg = gx * gridDim.y;
  int wg = blockIdx.y * gx + blockIdx.x;
  wg = (wg & 7) * (nwg >> 3) + (wg >> 3);
  const int by = wg / gx, bx = wg - by * gx;
  const int rowA0 = by * BM;
  const int rowB0 = bx * BN;
  const int wub = t & ~63;

  f32x4 acc[MT][NT];
#pragma unroll
  for (int m = 0; m < MT; ++m)
#pragma unroll
    for (int n = 0; n < NT; ++n) acc[m][n] = (f32x4){0.f, 0.f, 0.f, 0.f};

  auto stage = [&](int buf, int kt) {
#pragma unroll
    for (int rnd = 0; rnd < BM / 32; ++rnd) {
      const int idx = rnd * 256 + t;
      const int row = idx >> 3;
      const int cb = ((idx & 7) << 4) ^ ((row & 7) << 4);  // inverse-swizzled source
      const char* sa = (const char*)(A + (size_t)(rowA0 + row) * K + kt) + cb;
      gload16(sa, (char*)(&a_lds[buf][0]) + (size_t)(rnd * 256 + wub) * 16);
    }
#pragma unroll
    for (int rnd = 0; rnd < BN / 32; ++rnd) {
      const int idx = rnd * 256 + t;
      const int row = idx >> 3;
      const int cb = ((idx & 7) << 4) ^ ((row & 7) << 4);
      const char* sb = (const char*)(Bt + (size_t)(rowB0 + row) * K + kt) + cb;
      gload16(sb, (char*)(&b_lds[buf][0]) + (size_t)(rnd * 256 + wub) * 16);
    }
  };

  auto compute = [&](int buf) {
#pragma unroll
    for (int kb = 0; kb < 2; ++kb) {
      short8 af[MT], bfr[NT];
#pragma unroll
      for (int m = 0; m < MT; ++m) {
        int row = wr * WM + m * 16 + l15;
        int cb = (kb * 64 + l4 * 16) ^ ((row & 7) << 4);
        af[m] = *(const short8*)((const char*)(&a_lds[buf][0]) + row * 128 + cb);
      }
#pragma unroll
      for (int n = 0; n < NT; ++n) {
        int row = wc * WN + n * 16 + l15;
        int cb = (kb * 64 + l4 * 16) ^ ((row & 7) << 4);
        bfr[n] = *(const short8*)((const char*)(&b_lds[buf][0]) + row * 128 + cb);
      }
      __builtin_amdgcn_s_setprio(1);
#pragma unroll
      for (int m = 0; m < MT; ++m)
#pragma unroll
        for (int n = 0; n < NT; ++n)
          acc[m][n] = __builtin_amdgcn_mfma_f32_16x16x32_bf16(af[m], bfr[n], acc[m][n], 0, 0, 0);
      __builtin_amdgcn_s_setprio(0);
    }
  };

  if (PIPE) {
    stage(0, 0);
    __syncthreads();
    int cur = 0;
    for (int kt = 0; kt < K; kt += 64) {
      if (kt + 64 < K) stage(cur ^ 1, kt + 64);  // prefetch BEFORE compute
      compute(cur);
      __syncthreads();
      cur ^= 1;
    }
  } else {
    for (int kt = 0; kt < K; kt += 64) {
      stage(0, kt);
      __syncthreads();
      compute(0);
      __syncthreads();
    }
  }

#pragma unroll
  for (int n = 0; n < NT; ++n) {
    const int col = rowB0 + wc * WN + n * 16 + l15;
    const float bv = bias[col];
#pragma unroll
    for (int m = 0; m < MT; ++m) {
      const int row0 = rowA0 + wr * WM + m * 16 + l4 * 4;
#pragma unroll
      for (int r = 0; r < 4; ++r) {
        float v = acc[m][n][r] + bv;
        if (MODE == 0) {
          ((unsigned short*)outp)[(size_t)(row0 + r) * N + col] = f2bf(v);
        } else if (MODE == 1) {
          ((unsigned short*)outp)[(size_t)(row0 + r) * N + col] = f2bf(gelu_t(v));
        } else if (MODE == 2) {
          const size_t o = (size_t)(row0 + r) * N + col;
          float g = mod[(size_t)((row0 + r) >> 11) * 6144 + goff + col];
          ((float*)outp)[o] = res[o] + g * v;
        } else {  // MODE 3: qkv fused packing
          const int rr = row0 + r;
          if (rowB0 < 1024) {  // Q: row-major into qkvbuf
            ((unsigned short*)outp)[(size_t)rr * N + col] = f2bf(v);
          } else if (rowB0 < 2048) {  // K -> kpk fragment layout
            const int bb = rr >> 11, krow = rr & 2047;
            const int colk = col - 1024;
            const int hh = colk >> 6, d = colk & 63;
            const int bh2 = bb * 16 + hh;
            const size_t addr = (((size_t)(bh2 * 64 + (krow >> 5)) * 4 + (d >> 4)) * 512) +
                                (((d >> 3) & 1) * 32 + (krow & 31)) * 8 + (d & 7);
            kpkp[addr] = f2bf(v);
          } else {  // V -> vpk transposed fragment layout
            const int bb = rr >> 11, krow = rr & 2047;
            const int colv = col - 2048;
            const int hh = colv >> 6, d = colv & 63;
            const int bh2 = bb * 16 + hh;
            const int r5 = krow & 31;
            const int f = (d >> 5) * 2 + (r5 >> 4);
            const size_t addr = (((size_t)(bh2 * 64 + (krow >> 5)) * 4 + f) * 512) +
                                (((r5 >> 3) & 1) * 32 + (d & 31)) * 8 + (r5 & 7);
            vpkp[addr] = f2bf(v);
          }
        }
      }
    }
  }
}

// ---------------- flash attention, single-pass, fixed-reference softmax ----------------
// 512 blocks (2/CU), each covers ALL 64 k-tile-units (2048 keys) for 128 q-rows.
// Instruction-issue-bound (MFMA 31% + VALU 48%); k-split measured slower (R14).
// Q RoPE fused (head 0 only). Row-sum on matrix pipe; 1/lacc[0] is the normalizer.
__global__ __launch_bounds__(256) void attn_k(const unsigned short* __restrict__ qkv,
                                              const unsigned short* __restrict__ kpk,
                                              const unsigned short* __restrict__ vpk,
                                              const float* __restrict__ brp_all,
                                              unsigned short* __restrict__ ctxv) {
  const int t = threadIdx.x;
  const int w = t >> 6;
  const int lane = t & 63;
  const int l31 = lane & 31;
  const int hi = lane >> 5;
  // XCD-aware remap (512 blocks): each XCD owns 4 bh x 16 qt.
  const int wg = blockIdx.x;
  const int xcd = wg & 7, idx = wg >> 3;  // idx 0..63
  const int bh = xcd * 4 + (idx >> 4);
  const int qt = idx & 15;
  const int b = bh >> 4, h = bh & 15;
  const int qw = qt * 128 + w * 32;  // warp's q-base
  const float SC = 0.125f * 1.4426950408889634f;
  const float* brp = brp_all + (size_t)h * 4096;

  short8 qfr[4];
  {
    const unsigned short* qrow = qkv + (size_t)(b * SEQ + qw + l31) * 3072 + h * 64 + hi * 8;
#pragma unroll
    for (int kk = 0; kk < 4; ++kk) qfr[kk] = *(const short8*)(qrow + kk * 16);
    if (h == 0) {  // fused partial RoPE on Q (head 0 carries channels 0..63)
      const float pos = (float)(qw + l31);
#pragma unroll
      for (int kk = 0; kk < 4; ++kk) {
        const int d0 = kk * 16 + hi * 8;
#pragma unroll
        for (int m = 0; m < 4; ++m) rope_pair(qfr[kk], m, (d0 >> 1) + m, pos);
      }
    }
  }
  const float bfar_pos = brp[4095], bfar_neg = brp[0];
  const float* bql = brp + 2047 + 4 * hi - (qw + l31);

  short8 ones;  // bf16 1.0 x8 — A-operand for the row-sum MFMA
#pragma unroll
  for (int i = 0; i < 8; ++i) ones[i] = (short)0x3F80;

  const unsigned short* kp = kpk + ((size_t)(bh * 64)) * 2048 + lane * 8;
  const unsigned short* vp = vpk + ((size_t)(bh * 64)) * 2048 + lane * 8;

  short8 kfrA[4], vfrA[4], kfrB[4], vfrB[4];
#pragma unroll
  for (int s = 0; s < 4; ++s) {
    kfrA[s] = *(const short8*)(kp + s * 512);
    vfrA[s] = *(const short8*)(vp + s * 512);
  }
  kp += 2048;
  vp += 2048;

  f32x16 oacc0 = {}, oacc1 = {}, lacc = {};
  int kbase = 0;

#define ATTN_TILE(KF, VF, KFN, VFN)                                                       \
  do {                                                                                    \
    KFN[0] = *(const short8*)(kp);                                                        \
    KFN[1] = *(const short8*)(kp + 512);                                                  \
    KFN[2] = *(const short8*)(kp + 1024);                                                 \
    KFN[3] = *(const short8*)(kp + 1536);                                                 \
    VFN[0] = *(const short8*)(vp);                                                        \
    VFN[1] = *(const short8*)(vp + 512);                                                  \
    VFN[2] = *(const short8*)(vp + 1024);                                                 \
    VFN[3] = *(const short8*)(vp + 1536);                                                 \
    kp += 2048;                                                                           \
    vp += 2048;                                                                           \
    f32x16 sacc = {};                                                                     \
    sacc = __builtin_amdgcn_mfma_f32_32x32x16_bf16(KF[0], qfr[0], sacc, 0, 0, 0);         \
    sacc = __builtin_amdgcn_mfma_f32_32x32x16_bf16(KF[1], qfr[1], sacc, 0, 0, 0);         \
    sacc = __builtin_amdgcn_mfma_f32_32x32x16_bf16(KF[2], qfr[2], sacc, 0, 0, 0);         \
    sacc = __builtin_amdgcn_mfma_f32_32x32x16_bf16(KF[3], qfr[3], sacc, 0, 0, 0);         \
    float p[16];                                                                          \
    const int dd = kbase - qw;                                                            \
    if (dd >= 128 || dd <= -128) {                                                        \
      const float bf_ = (dd > 0) ? bfar_pos : bfar_neg;                                   \
      _Pragma("unroll") for (int r = 0; r < 16; ++r)                                      \
          p[r] = __builtin_amdgcn_exp2f(fmaf(sacc[r], SC, bf_));                          \
    } else {                                                                              \
      const float* bp = bql + kbase;                                                      \
      _Pragma("unroll") for (int r = 0; r < 16; ++r)                                      \
          p[r] = __builtin_amdgcn_exp2f(fmaf(sacc[r], SC, bp[(r & 3) + 8 * (r >> 2)]));   \
    }                                                                                     \
    unsigned int x0 = cvtpk(p[0], p[1]), x1 = cvtpk(p[2], p[3]);                          \
    unsigned int y0 = cvtpk(p[4], p[5]), y1 = cvtpk(p[6], p[7]);                          \
    asm("v_permlane32_swap_b32 %0, %1" : "+v"(x0), "+v"(y0));                             \
    asm("v_permlane32_swap_b32 %0, %1" : "+v"(x1), "+v"(y1));                             \
    unsigned int x2 = cvtpk(p[8], p[9]), x3 = cvtpk(p[10], p[11]);                        \
    unsigned int y2 = cvtpk(p[12], p[13]), y3 = cvtpk(p[14], p[15]);                      \
    asm("v_permlane32_swap_b32 %0, %1" : "+v"(x2), "+v"(y2));                             \
    asm("v_permlane32_swap_b32 %0, %1" : "+v"(x3), "+v"(y3));                             \
    int4v pi0 = {(int)x0, (int)x1, (int)y0, (int)y1};                                     \
    int4v pi1 = {(int)x2, (int)x3, (int)y2, (int)y3};                                     \
    short8 pf0 = __builtin_bit_cast(short8, pi0);                                         \
    short8 pf1 = __builtin_bit_cast(short8, pi1);                                         \
    lacc = __builtin_amdgcn_mfma_f32_32x32x16_bf16(ones, pf0, lacc, 0, 0, 0);             \
    lacc = __builtin_amdgcn_mfma_f32_32x32x16_bf16(ones, pf1, lacc, 0, 0, 0);             \
    oacc0 = __builtin_amdgcn_mfma_f32_32x32x16_bf16(VF[0], pf0, oacc0, 0, 0, 0);          \
    oacc0 = __builtin_amdgcn_mfma_f32_32x32x16_bf16(VF[1], pf1, oacc0, 0, 0, 0);          \
    oacc1 = __builtin_amdgcn_mfma_f32_32x32x16_bf16(VF[2], pf0, oacc1, 0, 0, 0);          \
    oacc1 = __builtin_amdgcn_mfma_f32_32x32x16_bf16(VF[3], pf1, oacc1, 0, 0, 0);          \
    kbase += 32;                                                                          \
  } while (0)

#pragma unroll 1
  for (int it = 0; it < 32; ++it) {  // 64 units = all 2048 keys
    ATTN_TILE(kfrA, vfrA, kfrB, vfrB);
    ATTN_TILE(kfrB, vfrB, kfrA, vfrA);
  }
#undef ATTN_TILE

  const float inv = 1.f / lacc[0];
  unsigned short* orow = ctxv + (size_t)(b * SEQ + qw + l31) * 1024 + h * 64;
#pragma unroll
  for (int r = 0; r < 16; r += 2) {
    const int d = (r & 3) + 8 * (r >> 2) + 4 * hi;
    *(unsigned int*)(orow + d) = cvtpk(oacc0[r] * inv, oacc0[r + 1] * inv);
    *(unsigned int*)(orow + 32 + d) = cvtpk(oacc1[r] * inv, oacc1[r + 1] * inv);
  }
}

// ---------------- launch ----------------
extern "C" void kernel_launch(void* const* d_in, const int* in_sizes, int n_in, void* d_out,
                              int out_size, void* d_ws, size_t ws_size, hipStream_t stream) {
  (void)in_sizes; (void)n_in; (void)out_size; (void)ws_size;
  const float* x = (const float*)d_in[0];
  const float* c = (const float*)d_in[1];
  const float* w_ada = (const float*)d_in[2];
  const float* b_ada = (const float*)d_in[3];
  const float* w_qkv = (const float*)d_in[4];
  const float* b_qkv = (const float*)d_in[5];
  const float* w_out = (const float*)d_in[6];
  const float* b_out = (const float*)d_in[7];
  const float* rel_t = (const float*)d_in[8];
  const float* w_mlp1 = (const float*)d_in[9];
  const float* b_mlp1 = (const float*)d_in[10];
  const float* w_mlp2 = (const float*)d_in[11];
  const float* b_mlp2 = (const float*)d_in[12];
  float* out = (float*)d_out;
  char* ws = (char*)d_ws;

  constexpr size_t OFF_WQKVT = 0;
  constexpr size_t OFF_WOUTT = OFF_WQKVT + (size_t)3072 * 1024 * 2;
  constexpr size_t OFF_WM1T = OFF_WOUTT + (size_t)1024 * 1024 * 2;
  constexpr size_t OFF_WM2T = OFF_WM1T + (size_t)4096 * 1024 * 2;
  constexpr size_t OFF_H = OFF_WM2T + (size_t)1024 * 4096 * 2;
  constexpr size_t OFF_QKV = OFF_H + (size_t)4096 * 1024 * 2;
  constexpr size_t OFF_VT = OFF_QKV + (size_t)4096 * 3072 * 2;   // vpk (8.4 MB)
  constexpr size_t OFF_CTXV = OFF_VT + (size_t)32 * 64 * 2048 * 2;
  constexpr size_t OFF_MID = OFF_CTXV + (size_t)4096 * 1024 * 2;  // kpk overlays MID[0:8.4M]
  constexpr size_t OFF_SILU = OFF_MID + (size_t)4096 * 4096 * 2;
  constexpr size_t OFF_MOD = OFF_SILU + 2048 * 4;
  constexpr size_t OFF_BRP = OFF_MOD + 12288 * 4;
  constexpr size_t OFF_PART = OFF_BRP + 65536 * 4;

  unsigned short* wqkvT = (unsigned short*)(ws + OFF_WQKVT);
  unsigned short* woutT = (unsigned short*)(ws + OFF_WOUTT);
  unsigned short* wm1T = (unsigned short*)(ws + OFF_WM1T);
  unsigned short* wm2T = (unsigned short*)(ws + OFF_WM2T);
  unsigned short* hbuf = (unsigned short*)(ws + OFF_H);
  unsigned short* qkvbuf = (unsigned short*)(ws + OFF_QKV);
  unsigned short* vpkbuf = (unsigned short*)(ws + OFF_VT);
  unsigned short* ctxvbuf = (unsigned short*)(ws + OFF_CTXV);
  unsigned short* midbuf = (unsigned short*)(ws + OFF_MID);
  unsigned short* kpkbuf = (unsigned short*)(ws + OFF_MID);  // dead region during attn
  float* siluc = (float*)(ws + OFF_SILU);
  float* modb = (float*)(ws + OFF_MOD);
  float* brp = (float*)(ws + OFF_BRP);
  float* part = (float*)(ws + OFF_PART);

  prep_transpose<<<12552, 256, 0, stream>>>(w_qkv, w_out, w_mlp1, w_mlp2, wqkvT, woutT, wm1T,
                                            wm2T, c, siluc, rel_t, brp);
  mod_part_k<<<768, 256, 0, stream>>>(siluc, w_ada, part);
  mod_reduce_k<<<48, 256, 0, stream>>>(part, b_ada, modb);

  ln_mod<<<4096, 256, 0, stream>>>(x, modb, hbuf, 0, 1024);
  // qkv GEMM with fused K/V fragment packing
  gemm_bt<3, 128, 128, 0><<<dim3(24, 32), 256, 0, stream>>>(hbuf, wqkvT, b_qkv, qkvbuf, nullptr,
                                                            nullptr, 0, 3072, 1024, kpkbuf,
                                                            vpkbuf);
  krope_fix<<<512, 256, 0, stream>>>(kpkbuf);
  attn_k<<<512, 256, 0, stream>>>(qkvbuf, kpkbuf, vpkbuf, brp, ctxvbuf);
  // x1 = x + g_msa * (ctxv @ w_out + b_out)  (64x64 PIPE=1: measured best)
  gemm_bt<2, 64, 64, 1><<<dim3(16, 64), 256, 0, stream>>>(ctxvbuf, woutT, b_out, out, x, modb,
                                                          2048, 1024, 1024, nullptr, nullptr);
  ln_mod<<<4096, 256, 0, stream>>>(out, modb, hbuf, 3072, 4096);
  gemm_bt<1, 128, 128, 0><<<dim3(32, 32), 256, 0, stream>>>(hbuf, wm1T, b_mlp1, midbuf, nullptr,
                                                            nullptr, 0, 4096, 1024, nullptr,
                                                            nullptr);
  // out = x1 + g_mlp * (mid @ w_mlp2 + b_mlp2)  (64x64 PIPE=1)
  gemm_bt<2, 64, 64, 1><<<dim3(16, 64), 256, 0, stream>>>(midbuf, wm2T, b_mlp2, out, out, modb,
                                                          5120, 1024, 4096, nullptr, nullptr);
}

// Round 20
// 235.551 us; speedup vs baseline: 1.1904x; 1.0138x over previous
//
#include <hip/hip_runtime.h>
#include <hip/hip_bf16.h>

#define SEQ 2048

typedef float f32x4 __attribute__((ext_vector_type(4)));
typedef float f32x16 __attribute__((ext_vector_type(16)));
typedef short short8 __attribute__((ext_vector_type(8)));
typedef int int4v __attribute__((ext_vector_type(4)));

static __device__ __forceinline__ unsigned short f2bf(float f) {
  __hip_bfloat16 h = __float2bfloat16(f);
  unsigned short u;
  __builtin_memcpy(&u, &h, 2);
  return u;
}
static __device__ __forceinline__ float bf2f(unsigned short u) {
  __hip_bfloat16 h;
  __builtin_memcpy(&h, &u, 2);
  return __bfloat162float(h);
}
static __device__ __forceinline__ void gload16(const void* g, void* l) {
  __builtin_amdgcn_global_load_lds(
      (const __attribute__((address_space(1))) void*)g,
      (__attribute__((address_space(3))) void*)l, 16, 0, 0);
}
// gelu(tanh approx) == x * sigmoid(1.59577x + 0.0713548x^3), sigmoid in exp2 domain
static __device__ __forceinline__ float gelu_t(float x) {
  float t = x * x;
  float z = x * fmaf(0.1029442695044937f, t, 2.3021181827964594f);  // pre-multiplied log2(e)
  return x * __builtin_amdgcn_rcpf(1.f + exp2f(-z));
}
static __device__ __forceinline__ unsigned int cvtpk(float lo, float hi) {
  unsigned int r;
  asm("v_cvt_pk_bf16_f32 %0, %1, %2" : "=v"(r) : "v"(lo), "v"(hi));
  return r;
}
// partial RoPE pair rotation for channel pair (2i, 2i+1) at sequence position pos
static __device__ __forceinline__ void rope_pair(short8& v, int m, int i, float pos) {
  const float fr = exp2f(-(float)(2 * i) * (13.287712379549449f / 64.f));  // 10000^(-2i/64)
  const float ang = pos * fr;
  const float sn = sinf(ang), cs = cosf(ang);
  const float x0 = bf2f((unsigned short)v[2 * m]);
  const float x1 = bf2f((unsigned short)v[2 * m + 1]);
  v[2 * m] = (short)f2bf(x0 * cs - x1 * sn);
  v[2 * m + 1] = (short)f2bf(x1 * cs + x0 * sn);
}

// ---------------- prep kernels ----------------

#define SOFTMAX_M0 16.0f
// merged: 4x weight transpose (blocks 0..12287) + silu(c) (12288..12295) +
// rel-position bias table (12296..12551). brp pre-scaled by log2(e), pre-shifted -M0.
__global__ void prep_transpose(const float* __restrict__ w_qkv, const float* __restrict__ w_out,
                               const float* __restrict__ w_mlp1, const float* __restrict__ w_mlp2,
                               unsigned short* __restrict__ dq, unsigned short* __restrict__ dwo,
                               unsigned short* __restrict__ dm1, unsigned short* __restrict__ dm2,
                               const float* __restrict__ c, float* __restrict__ siluc,
                               const float* __restrict__ rel_table, float* __restrict__ brp) {
  const int bid = blockIdx.x;
  const int t = threadIdx.x;
  if (bid >= 12288) {
    const int pb = bid - 12288;
    if (pb < 8) {
      int i = pb * 256 + t;  // 2048
      float v = c[i];
      siluc[i] = v / (1.f + expf(-v));
    } else {
      int idx = (pb - 8) * 256 + t;  // 16*4096
      int h = idx >> 12, pos = idx & 4095;
      int rp = pos - 2047;
      int bucket = rp > 0 ? 16 : 0;
      int a = rp < 0 ? -rp : rp;
      int bi;
      if (a < 8) {
        bi = a;
      } else {
        bi = 8 + (int)(logf((float)a / 8.f) / 2.772588722239781f * 8.f);
        if (bi > 15) bi = 15;
      }
      brp[idx] = rel_table[(bucket + bi) * 16 + h] * 1.4426950408889634f - SOFTMAX_M0;
    }
    return;
  }
  __shared__ float tile[32][33];
  const float* src;
  unsigned short* dst;
  int K, N, NT, r;
  if (bid < 3072) {
    src = w_qkv; dst = dq; K = 1024; N = 3072; NT = 96; r = bid;
  } else if (bid < 4096) {
    src = w_out; dst = dwo; K = 1024; N = 1024; NT = 32; r = bid - 3072;
  } else if (bid < 8192) {
    src = w_mlp1; dst = dm1; K = 1024; N = 4096; NT = 128; r = bid - 4096;
  } else {
    src = w_mlp2; dst = dm2; K = 4096; N = 1024; NT = 32; r = bid - 8192;
  }
  const int nt = r % NT, kt = r / NT;
  const int col = t & 31, r0 = t >> 5;
#pragma unroll
  for (int i = 0; i < 4; ++i) {
    int rr = r0 + i * 8;
    tile[rr][col] = src[(size_t)(kt * 32 + rr) * N + nt * 32 + col];
  }
  __syncthreads();
#pragma unroll
  for (int i = 0; i < 4; ++i) {
    int rr = r0 + i * 8;
    dst[(size_t)(nt * 32 + rr) * K + kt * 32 + col] = f2bf(tile[col][rr]);
  }
}

// partial mod GEMM: silu(c)[2,1024] @ w_ada[1024,6144] split over 16 K-chunks
// (768 blocks = 3072 waves; single-kernel 48-block variant measured 80us, R17)
__global__ void mod_part_k(const float* __restrict__ siluc, const float* __restrict__ w_ada,
                           float* __restrict__ part) {
  int gid = blockIdx.x * 256 + threadIdx.x;  // 16*12288
  int kc = gid / 12288;
  int idx = gid - kc * 12288;
  int b = idx / 6144;
  int j = idx - b * 6144;
  const float* cp = siluc + b * 1024 + kc * 64;
  const float* wp = w_ada + (size_t)kc * 64 * 6144 + j;
  float acc = 0.f;
#pragma unroll 8
  for (int k = 0; k < 64; ++k) acc += cp[k] * wp[(size_t)k * 6144];
  part[gid] = acc;
}

__global__ void mod_reduce_k(const float* __restrict__ part, const float* __restrict__ b_ada,
                             float* __restrict__ mod) {
  int idx = blockIdx.x * 256 + threadIdx.x;  // 12288
  int j = idx % 6144;
  float a = b_ada[j];
#pragma unroll
  for (int kc = 0; kc < 16; ++kc) a += part[kc * 12288 + idx];
  mod[idx] = a;
}

// LayerNorm + adaLN modulation -> bf16
__global__ void ln_mod(const float* __restrict__ x, const float* __restrict__ mod,
                       unsigned short* __restrict__ out, int sh_off, int sc_off) {
  int row = blockIdx.x;
  int b = row >> 11;
  int t = threadIdx.x;
  const float4 v = ((const float4*)(x + (size_t)row * 1024))[t];
  float s1 = v.x + v.y + v.z + v.w;
  float s2 = v.x * v.x + v.y * v.y + v.z * v.z + v.w * v.w;
#pragma unroll
  for (int off = 32; off; off >>= 1) {
    s1 += __shfl_xor(s1, off);
    s2 += __shfl_xor(s2, off);
  }
  __shared__ float red[8];
  int w = t >> 6, lane = t & 63;
  if (lane == 0) { red[w] = s1; red[4 + w] = s2; }
  __syncthreads();
  s1 = red[0] + red[1] + red[2] + red[3];
  s2 = red[4] + red[5] + red[6] + red[7];
  float mean = s1 * (1.f / 1024.f);
  float var = s2 * (1.f / 1024.f) - mean * mean;
  float rstd = rsqrtf(var + 1e-6f);
  const float* mb = mod + (size_t)b * 6144;
  int col = t * 4;
  ushort4 o4;
  o4.x = f2bf((v.x - mean) * rstd * (1.f + mb[sc_off + col + 0]) + mb[sh_off + col + 0]);
  o4.y = f2bf((v.y - mean) * rstd * (1.f + mb[sc_off + col + 1]) + mb[sh_off + col + 1]);
  o4.z = f2bf((v.z - mean) * rstd * (1.f + mb[sc_off + col + 2]) + mb[sh_off + col + 2]);
  o4.w = f2bf((v.w - mean) * rstd * (1.f + mb[sc_off + col + 3]) + mb[sh_off + col + 3]);
  *((ushort4*)(out + (size_t)row * 1024 + col)) = o4;
}

// In-place partial RoPE on kpk head 0 (reference ropes channels 0..63 only).
__global__ void krope_fix(unsigned short* __restrict__ kpk) {
  const int gid = blockIdx.x * 256 + threadIdx.x;  // 2*64*32*32 = 131072
  const int i = gid & 31;                          // pair index (d = 2i)
  const int l31 = (gid >> 5) & 31;
  const int kt = (gid >> 10) & 63;
  const int b = gid >> 16;
  const int d = 2 * i;
  const int bh = b * 16;  // h = 0
  const size_t addr = (((size_t)(bh * 64 + kt) * 4 + (d >> 4)) * 512) +
                      (((d >> 3) & 1) * 32 + l31) * 8 + (d & 7);
  unsigned int pv = *(unsigned int*)(kpk + addr);
  const float x0 = bf2f((unsigned short)(pv & 0xFFFF));
  const float x1 = bf2f((unsigned short)(pv >> 16));
  const float fr = exp2f(-(float)d * (13.287712379549449f / 64.f));
  const float ang = (float)(kt * 32 + l31) * fr;
  const float sn = sinf(ang), cs = cosf(ang);
  *(unsigned int*)(kpk + addr) =
      (unsigned int)f2bf(x0 * cs - x1 * sn) | ((unsigned int)f2bf(x1 * cs + x0 * sn) << 16);
}

// ---------------- GEMM: C = A[M,K] * Bt[N,K]^T, bf16 in, fused epilogues ----------------
// MODE 0: bf16 = acc + bias; MODE 1: bf16 = gelu(acc+bias); MODE 2: f32 = res + g*(acc+bias)
// MODE 3: qkv fused packing — Q -> qkvbuf row-major; K -> kpk fragment layout; V -> vpk
//         transposed fragment layout (block-uniform region branch).
// KS=64 (measured conflict-free swizzle). PIPE=1: double-buffered LDS, STAGE(t+1) before
// compute(t). MEASURED tile ledger (N=1024 GEMMs): 64x64 PIPE=1 = 55us best (R9/R11);
// 128x64=60.6 (R10); packed-B=68.5 (R12); 128x128 PIPE=1=71.3 (R13). Do not revisit.
template <int MODE, int BM, int BN, int PIPE>
__global__ __launch_bounds__(256) void gemm_bt(
    const unsigned short* __restrict__ A, const unsigned short* __restrict__ Bt,
    const float* __restrict__ bias, void* __restrict__ outp, const float* __restrict__ res,
    const float* __restrict__ mod, int goff, int N, int K,
    unsigned short* __restrict__ kpkp, unsigned short* __restrict__ vpkp) {
  constexpr int NBUF = PIPE ? 2 : 1;
  __shared__ __align__(16) unsigned short a_lds[NBUF][BM * 64];
  __shared__ __align__(16) unsigned short b_lds[NBUF][BN * 64];
  constexpr int WM = BM / 2, WN = BN / 2;
  constexpr int MT = WM / 16, NT = WN / 16;
  const int t = threadIdx.x;
  const int lane = t & 63;
  const int l15 = lane & 15, l4 = lane >> 4;
  const int w = t >> 6;
  const int wr = w >> 1, wc = w & 1;
  // XCD-aware bijective remap (requires nwg % 8 == 0).
  const int gx = gridDim.x;
  const int nwg = gx * gridDim.y;
  int wg = blockIdx.y * gx + blockIdx.x;
  wg = (wg & 7) * (nwg >> 3) + (wg >> 3);
  const int by = wg / gx, bx = wg - by * gx;
  const int rowA0 = by * BM;
  const int rowB0 = bx * BN;
  const int wub = t & ~63;

  f32x4 acc[MT][NT];
#pragma unroll
  for (int m = 0; m < MT; ++m)
#pragma unroll
    for (int n = 0; n < NT; ++n) acc[m][n] = (f32x4){0.f, 0.f, 0.f, 0.f};

  auto stage = [&](int buf, int kt) {
#pragma unroll
    for (int rnd = 0; rnd < BM / 32; ++rnd) {
      const int idx = rnd * 256 + t;
      const int row = idx >> 3;
      const int cb = ((idx & 7) << 4) ^ ((row & 7) << 4);  // inverse-swizzled source
      const char* sa = (const char*)(A + (size_t)(rowA0 + row) * K + kt) + cb;
      gload16(sa, (char*)(&a_lds[buf][0]) + (size_t)(rnd * 256 + wub) * 16);
    }
#pragma unroll
    for (int rnd = 0; rnd < BN / 32; ++rnd) {
      const int idx = rnd * 256 + t;
      const int row = idx >> 3;
      const int cb = ((idx & 7) << 4) ^ ((row & 7) << 4);
      const char* sb = (const char*)(Bt + (size_t)(rowB0 + row) * K + kt) + cb;
      gload16(sb, (char*)(&b_lds[buf][0]) + (size_t)(rnd * 256 + wub) * 16);
    }
  };

  auto compute = [&](int buf) {
#pragma unroll
    for (int kb = 0; kb < 2; ++kb) {
      short8 af[MT], bfr[NT];
#pragma unroll
      for (int m = 0; m < MT; ++m) {
        int row = wr * WM + m * 16 + l15;
        int cb = (kb * 64 + l4 * 16) ^ ((row & 7) << 4);
        af[m] = *(const short8*)((const char*)(&a_lds[buf][0]) + row * 128 + cb);
      }
#pragma unroll
      for (int n = 0; n < NT; ++n) {
        int row = wc * WN + n * 16 + l15;
        int cb = (kb * 64 + l4 * 16) ^ ((row & 7) << 4);
        bfr[n] = *(const short8*)((const char*)(&b_lds[buf][0]) + row * 128 + cb);
      }
      __builtin_amdgcn_s_setprio(1);
#pragma unroll
      for (int m = 0; m < MT; ++m)
#pragma unroll
        for (int n = 0; n < NT; ++n)
          acc[m][n] = __builtin_amdgcn_mfma_f32_16x16x32_bf16(af[m], bfr[n], acc[m][n], 0, 0, 0);
      __builtin_amdgcn_s_setprio(0);
    }
  };

  if (PIPE) {
    stage(0, 0);
    __syncthreads();
    int cur = 0;
    for (int kt = 0; kt < K; kt += 64) {
      if (kt + 64 < K) stage(cur ^ 1, kt + 64);  // prefetch BEFORE compute
      compute(cur);
      __syncthreads();
      cur ^= 1;
    }
  } else {
    for (int kt = 0; kt < K; kt += 64) {
      stage(0, kt);
      __syncthreads();
      compute(0);
      __syncthreads();
    }
  }

#pragma unroll
  for (int n = 0; n < NT; ++n) {
    const int col = rowB0 + wc * WN + n * 16 + l15;
    const float bv = bias[col];
#pragma unroll
    for (int m = 0; m < MT; ++m) {
      const int row0 = rowA0 + wr * WM + m * 16 + l4 * 4;
#pragma unroll
      for (int r = 0; r < 4; ++r) {
        float v = acc[m][n][r] + bv;
        if (MODE == 0) {
          ((unsigned short*)outp)[(size_t)(row0 + r) * N + col] = f2bf(v);
        } else if (MODE == 1) {
          ((unsigned short*)outp)[(size_t)(row0 + r) * N + col] = f2bf(gelu_t(v));
        } else if (MODE == 2) {
          const size_t o = (size_t)(row0 + r) * N + col;
          float g = mod[(size_t)((row0 + r) >> 11) * 6144 + goff + col];
          ((float*)outp)[o] = res[o] + g * v;
        } else {  // MODE 3: qkv fused packing
          const int rr = row0 + r;
          if (rowB0 < 1024) {  // Q: row-major into qkvbuf
            ((unsigned short*)outp)[(size_t)rr * N + col] = f2bf(v);
          } else if (rowB0 < 2048) {  // K -> kpk fragment layout
            const int bb = rr >> 11, krow = rr & 2047;
            const int colk = col - 1024;
            const int hh = colk >> 6, d = colk & 63;
            const int bh2 = bb * 16 + hh;
            const size_t addr = (((size_t)(bh2 * 64 + (krow >> 5)) * 4 + (d >> 4)) * 512) +
                                (((d >> 3) & 1) * 32 + (krow & 31)) * 8 + (d & 7);
            kpkp[addr] = f2bf(v);
          } else {  // V -> vpk transposed fragment layout
            const int bb = rr >> 11, krow = rr & 2047;
            const int colv = col - 2048;
            const int hh = colv >> 6, d = colv & 63;
            const int bh2 = bb * 16 + hh;
            const int r5 = krow & 31;
            const int f = (d >> 5) * 2 + (r5 >> 4);
            const size_t addr = (((size_t)(bh2 * 64 + (krow >> 5)) * 4 + f) * 512) +
                                (((r5 >> 3) & 1) * 32 + (d & 31)) * 8 + (r5 & 7);
            vpkp[addr] = f2bf(v);
          }
        }
      }
    }
  }
}

// ---------------- flash attention, single-pass, T15 double-pipeline ----------------
// 512 blocks (2/CU), each covers ALL 64 k-tile-units (2048 keys) for 128 q-rows.
// T15 (m214-v36): two S-tiles live — QK(t+1) issues BEFORE softmax(t), giving the
// sacc->VALU dependency a full phase of distance so each wave's own VALU covers its
// own MFMA latency (was: serial QK->SM chain, 79% combined issue). Explicit A/B
// register state (static indexing). Q RoPE fused (head 0). Row-sum on matrix pipe.
__global__ __launch_bounds__(256) void attn_k(const unsigned short* __restrict__ qkv,
                                              const unsigned short* __restrict__ kpk,
                                              const unsigned short* __restrict__ vpk,
                                              const float* __restrict__ brp_all,
                                              unsigned short* __restrict__ ctxv) {
  const int t = threadIdx.x;
  const int w = t >> 6;
  const int lane = t & 63;
  const int l31 = lane & 31;
  const int hi = lane >> 5;
  // XCD-aware remap (512 blocks): each XCD owns 4 bh x 16 qt.
  const int wg = blockIdx.x;
  const int xcd = wg & 7, idx = wg >> 3;  // idx 0..63
  const int bh = xcd * 4 + (idx >> 4);
  const int qt = idx & 15;
  const int b = bh >> 4, h = bh & 15;
  const int qw = qt * 128 + w * 32;  // warp's q-base
  const float SC = 0.125f * 1.4426950408889634f;
  const float* brp = brp_all + (size_t)h * 4096;

  short8 qfr[4];
  {
    const unsigned short* qrow = qkv + (size_t)(b * SEQ + qw + l31) * 3072 + h * 64 + hi * 8;
#pragma unroll
    for (int kk = 0; kk < 4; ++kk) qfr[kk] = *(const short8*)(qrow + kk * 16);
    if (h == 0) {  // fused partial RoPE on Q (head 0 carries channels 0..63)
      const float pos = (float)(qw + l31);
#pragma unroll
      for (int kk = 0; kk < 4; ++kk) {
        const int d0 = kk * 16 + hi * 8;
#pragma unroll
        for (int m = 0; m < 4; ++m) rope_pair(qfr[kk], m, (d0 >> 1) + m, pos);
      }
    }
  }
  const float bfar_pos = brp[4095], bfar_neg = brp[0];
  const float* bql = brp + 2047 + 4 * hi - (qw + l31);

  short8 ones;  // bf16 1.0 x8 — A-operand for the row-sum MFMA
#pragma unroll
  for (int i = 0; i < 8; ++i) ones[i] = (short)0x3F80;

  const unsigned short* kp = kpk + ((size_t)(bh * 64)) * 2048 + lane * 8;
  const unsigned short* vp = vpk + ((size_t)(bh * 64)) * 2048 + lane * 8;

  short8 kfrA[4], vfrA[4], kfrB[4], vfrB[4];
  // prologue: load unit 0 -> A, unit 1 -> B
#pragma unroll
  for (int s = 0; s < 4; ++s) {
    kfrA[s] = *(const short8*)(kp + s * 512);
    vfrA[s] = *(const short8*)(vp + s * 512);
  }
  kp += 2048;
  vp += 2048;
#pragma unroll
  for (int s = 0; s < 4; ++s) {
    kfrB[s] = *(const short8*)(kp + s * 512);
    vfrB[s] = *(const short8*)(vp + s * 512);
  }
  kp += 2048;
  vp += 2048;

  f32x16 oacc0 = {}, oacc1 = {}, lacc = {}, saccA = {}, saccB = {};

#define QK_COMP(SACC, KF)                                                           \
  do {                                                                              \
    f32x16 z_ = {};                                                                 \
    z_ = __builtin_amdgcn_mfma_f32_32x32x16_bf16(KF[0], qfr[0], z_, 0, 0, 0);       \
    z_ = __builtin_amdgcn_mfma_f32_32x32x16_bf16(KF[1], qfr[1], z_, 0, 0, 0);       \
    z_ = __builtin_amdgcn_mfma_f32_32x32x16_bf16(KF[2], qfr[2], z_, 0, 0, 0);       \
    z_ = __builtin_amdgcn_mfma_f32_32x32x16_bf16(KF[3], qfr[3], z_, 0, 0, 0);       \
    SACC = z_;                                                                      \
  } while (0)

#define LOADK(KF)                                                                   \
  do {                                                                              \
    KF[0] = *(const short8*)(kp);                                                   \
    KF[1] = *(const short8*)(kp + 512);                                             \
    KF[2] = *(const short8*)(kp + 1024);                                            \
    KF[3] = *(const short8*)(kp + 1536);                                            \
  } while (0)

#define LOADV(VF)                                                                   \
  do {                                                                              \
    VF[0] = *(const short8*)(vp);                                                   \
    VF[1] = *(const short8*)(vp + 512);                                             \
    VF[2] = *(const short8*)(vp + 1024);                                            \
    VF[3] = *(const short8*)(vp + 1536);                                            \
  } while (0)

#define SM_PV(SACC, VF, KB)                                                              \
  do {                                                                                   \
    float p[16];                                                                         \
    const int dd = (KB)-qw;                                                              \
    if (dd >= 128 || dd <= -128) {                                                       \
      const float bf_ = (dd > 0) ? bfar_pos : bfar_neg;                                  \
      _Pragma("unroll") for (int r = 0; r < 16; ++r)                                     \
          p[r] = __builtin_amdgcn_exp2f(fmaf(SACC[r], SC, bf_));                         \
    } else {                                                                             \
      const float* bp = bql + (KB);                                                      \
      _Pragma("unroll") for (int r = 0; r < 16; ++r)                                     \
          p[r] = __builtin_amdgcn_exp2f(fmaf(SACC[r], SC, bp[(r & 3) + 8 * (r >> 2)]));  \
    }                                                                                    \
    unsigned int x0 = cvtpk(p[0], p[1]), x1 = cvtpk(p[2], p[3]);                         \
    unsigned int y0 = cvtpk(p[4], p[5]), y1 = cvtpk(p[6], p[7]);                         \
    asm("v_permlane32_swap_b32 %0, %1" : "+v"(x0), "+v"(y0));                            \
    asm("v_permlane32_swap_b32 %0, %1" : "+v"(x1), "+v"(y1));                            \
    unsigned int x2 = cvtpk(p[8], p[9]), x3 = cvtpk(p[10], p[11]);                       \
    unsigned int y2 = cvtpk(p[12], p[13]), y3 = cvtpk(p[14], p[15]);                     \
    asm("v_permlane32_swap_b32 %0, %1" : "+v"(x2), "+v"(y2));                            \
    asm("v_permlane32_swap_b32 %0, %1" : "+v"(x3), "+v"(y3));                            \
    int4v pi0 = {(int)x0, (int)x1, (int)y0, (int)y1};                                    \
    int4v pi1 = {(int)x2, (int)x3, (int)y2, (int)y3};                                    \
    short8 pf0 = __builtin_bit_cast(short8, pi0);                                        \
    short8 pf1 = __builtin_bit_cast(short8, pi1);                                        \
    lacc = __builtin_amdgcn_mfma_f32_32x32x16_bf16(ones, pf0, lacc, 0, 0, 0);            \
    lacc = __builtin_amdgcn_mfma_f32_32x32x16_bf16(ones, pf1, lacc, 0, 0, 0);            \
    oacc0 = __builtin_amdgcn_mfma_f32_32x32x16_bf16(VF[0], pf0, oacc0, 0, 0, 0);         \
    oacc0 = __builtin_amdgcn_mfma_f32_32x32x16_bf16(VF[1], pf1, oacc0, 0, 0, 0);         \
    oacc1 = __builtin_amdgcn_mfma_f32_32x32x16_bf16(VF[2], pf0, oacc1, 0, 0, 0);         \
    oacc1 = __builtin_amdgcn_mfma_f32_32x32x16_bf16(VF[3], pf1, oacc1, 0, 0, 0);         \
  } while (0)

  // prologue QK for unit 0
  QK_COMP(saccA, kfrA);

  // T15 pipeline: per half — QK(next) || load(next+1) || SM_PV(cur).
  // State at loop top: saccA = QK(2i) done; kfrB/vfrB = unit 2i+1; ptrs at 2i+2.
#pragma unroll 1
  for (int it = 0; it < 31; ++it) {
    // half 1: process unit 2i
    QK_COMP(saccB, kfrB);       // unit 2i+1 (loaded one full phase ago)
    LOADK(kfrA);                // K of unit 2i+2 (kfrA dead: QK(2i) consumed)
    SM_PV(saccA, vfrA, it * 64);
    LOADV(vfrA);                // V of unit 2i+2 (vfrA dead after SM_PV)
    kp += 2048;
    vp += 2048;
    // half 2: process unit 2i+1
    QK_COMP(saccA, kfrA);       // unit 2i+2
    LOADK(kfrB);                // K of unit 2i+3
    SM_PV(saccB, vfrB, it * 64 + 32);
    LOADV(vfrB);                // V of unit 2i+3
    kp += 2048;
    vp += 2048;
  }
  // epilogue: saccA = QK(62); kfrB/vfrB = unit 63
  QK_COMP(saccB, kfrB);
  SM_PV(saccA, vfrA, 1984);
  SM_PV(saccB, vfrB, 2016);

#undef QK_COMP
#undef LOADK
#undef LOADV
#undef SM_PV

  const float inv = 1.f / lacc[0];
  unsigned short* orow = ctxv + (size_t)(b * SEQ + qw + l31) * 1024 + h * 64;
#pragma unroll
  for (int r = 0; r < 16; r += 2) {
    const int d = (r & 3) + 8 * (r >> 2) + 4 * hi;
    *(unsigned int*)(orow + d) = cvtpk(oacc0[r] * inv, oacc0[r + 1] * inv);
    *(unsigned int*)(orow + 32 + d) = cvtpk(oacc1[r] * inv, oacc1[r + 1] * inv);
  }
}

// ---------------- launch ----------------
extern "C" void kernel_launch(void* const* d_in, const int* in_sizes, int n_in, void* d_out,
                              int out_size, void* d_ws, size_t ws_size, hipStream_t stream) {
  (void)in_sizes; (void)n_in; (void)out_size; (void)ws_size;
  const float* x = (const float*)d_in[0];
  const float* c = (const float*)d_in[1];
  const float* w_ada = (const float*)d_in[2];
  const float* b_ada = (const float*)d_in[3];
  const float* w_qkv = (const float*)d_in[4];
  const float* b_qkv = (const float*)d_in[5];
  const float* w_out = (const float*)d_in[6];
  const float* b_out = (const float*)d_in[7];
  const float* rel_t = (const float*)d_in[8];
  const float* w_mlp1 = (const float*)d_in[9];
  const float* b_mlp1 = (const float*)d_in[10];
  const float* w_mlp2 = (const float*)d_in[11];
  const float* b_mlp2 = (const float*)d_in[12];
  float* out = (float*)d_out;
  char* ws = (char*)d_ws;

  constexpr size_t OFF_WQKVT = 0;
  constexpr size_t OFF_WOUTT = OFF_WQKVT + (size_t)3072 * 1024 * 2;
  constexpr size_t OFF_WM1T = OFF_WOUTT + (size_t)1024 * 1024 * 2;
  constexpr size_t OFF_WM2T = OFF_WM1T + (size_t)4096 * 1024 * 2;
  constexpr size_t OFF_H = OFF_WM2T + (size_t)1024 * 4096 * 2;
  constexpr size_t OFF_QKV = OFF_H + (size_t)4096 * 1024 * 2;
  constexpr size_t OFF_VT = OFF_QKV + (size_t)4096 * 3072 * 2;   // vpk (8.4 MB)
  constexpr size_t OFF_CTXV = OFF_VT + (size_t)32 * 64 * 2048 * 2;
  constexpr size_t OFF_MID = OFF_CTXV + (size_t)4096 * 1024 * 2;  // kpk overlays MID[0:8.4M]
  constexpr size_t OFF_SILU = OFF_MID + (size_t)4096 * 4096 * 2;
  constexpr size_t OFF_MOD = OFF_SILU + 2048 * 4;
  constexpr size_t OFF_BRP = OFF_MOD + 12288 * 4;
  constexpr size_t OFF_PART = OFF_BRP + 65536 * 4;

  unsigned short* wqkvT = (unsigned short*)(ws + OFF_WQKVT);
  unsigned short* woutT = (unsigned short*)(ws + OFF_WOUTT);
  unsigned short* wm1T = (unsigned short*)(ws + OFF_WM1T);
  unsigned short* wm2T = (unsigned short*)(ws + OFF_WM2T);
  unsigned short* hbuf = (unsigned short*)(ws + OFF_H);
  unsigned short* qkvbuf = (unsigned short*)(ws + OFF_QKV);
  unsigned short* vpkbuf = (unsigned short*)(ws + OFF_VT);
  unsigned short* ctxvbuf = (unsigned short*)(ws + OFF_CTXV);
  unsigned short* midbuf = (unsigned short*)(ws + OFF_MID);
  unsigned short* kpkbuf = (unsigned short*)(ws + OFF_MID);  // dead region during attn
  float* siluc = (float*)(ws + OFF_SILU);
  float* modb = (float*)(ws + OFF_MOD);
  float* brp = (float*)(ws + OFF_BRP);
  float* part = (float*)(ws + OFF_PART);

  prep_transpose<<<12552, 256, 0, stream>>>(w_qkv, w_out, w_mlp1, w_mlp2, wqkvT, woutT, wm1T,
                                            wm2T, c, siluc, rel_t, brp);
  mod_part_k<<<768, 256, 0, stream>>>(siluc, w_ada, part);
  mod_reduce_k<<<48, 256, 0, stream>>>(part, b_ada, modb);

  ln_mod<<<4096, 256, 0, stream>>>(x, modb, hbuf, 0, 1024);
  // qkv GEMM with fused K/V fragment packing
  gemm_bt<3, 128, 128, 0><<<dim3(24, 32), 256, 0, stream>>>(hbuf, wqkvT, b_qkv, qkvbuf, nullptr,
                                                            nullptr, 0, 3072, 1024, kpkbuf,
                                                            vpkbuf);
  krope_fix<<<512, 256, 0, stream>>>(kpkbuf);
  attn_k<<<512, 256, 0, stream>>>(qkvbuf, kpkbuf, vpkbuf, brp, ctxvbuf);
  // x1 = x + g_msa * (ctxv @ w_out + b_out)  (64x64 PIPE=1: measured best)
  gemm_bt<2, 64, 64, 1><<<dim3(16, 64), 256, 0, stream>>>(ctxvbuf, woutT, b_out, out, x, modb,
                                                          2048, 1024, 1024, nullptr, nullptr);
  ln_mod<<<4096, 256, 0, stream>>>(out, modb, hbuf, 3072, 4096);
  gemm_bt<1, 128, 128, 0><<<dim3(32, 32), 256, 0, stream>>>(hbuf, wm1T, b_mlp1, midbuf, nullptr,
                                                            nullptr, 0, 4096, 1024, nullptr,
                                                            nullptr);
  // out = x1 + g_mlp * (mid @ w_mlp2 + b_mlp2)  (64x64 PIPE=1)
  gemm_bt<2, 64, 64, 1><<<dim3(16, 64), 256, 0, stream>>>(midbuf, wm2T, b_mlp2, out, out, modb,
                                                          5120, 1024, 4096, nullptr, nullptr);
}